// Round 8
// baseline (394.737 us; speedup 1.0000x reference)
//
#include <hip/hip_runtime.h>
#include <hip/hip_bf16.h>

#define TT 512
#define II 46
#define HH 64
#define GG 192
#define CC 8
#define KP 128   // fused K per gate: [h (64) | x (46, zero-padded to 64)]

typedef __attribute__((ext_vector_type(8))) _Float16 half8;
typedef __attribute__((ext_vector_type(4))) float float4v;

__device__ inline float fsigm(float xv) {
  return __builtin_amdgcn_rcpf(1.f + __expf(-xv));
}
// tanh(x) = 1 - 2/(1 + e^{2x}); saturates correctly at +-1, branch-free
__device__ inline float ftanh2(float xv) {
  float e = __expf(2.f * xv);
  return __builtin_fmaf(-2.f, __builtin_amdgcn_rcpf(1.f + e), 1.f);
}

// wp[u][k] f16, u in [0,192): k<64 -> w_hh[u][k]; 64<=k<110 -> w_ih[u][k-64]; else 0.
__global__ void pack_w(const float* __restrict__ w_ih, const float* __restrict__ w_hh,
                       _Float16* __restrict__ wp) {
  int idx = blockIdx.x * 256 + threadIdx.x;  // 192*128 = 24576 exact
  int u = idx >> 7, k = idx & 127;
  float v = (k < HH) ? w_hh[u * HH + k]
                     : ((k < HH + II) ? w_ih[u * II + (k - HH)] : 0.f);
  wp[idx] = (_Float16)v;
}

// One wave (64 threads) per block; block owns batch rows p0=2*bid, p0+1.
// No barriers anywhere: all LDS traffic is intra-wave, ordered by lgkmcnt(0).
// A-frag trick: h rows replicated at M-rows {0,1,4,5,8,9,12,13} (lane reads
// row (m16&1) if (m16&3)<2 else zero-row 2). C of tile (gamma,g) then holds,
// in EVERY kg-quadrant, rows {0,1} at elems {0,1} for unit 16g+m16 -> lane
// (kg,m16) selects g=kg and owns unit us=16kg+m16 x 2 rows. Zero shuffles.
__launch_bounds__(64, 1)
__global__ void gru_main(const float* __restrict__ x,
                         const float* __restrict__ b_ih, const float* __restrict__ b_hh,
                         const float* __restrict__ fc_w, const float* __restrict__ fc_b,
                         const _Float16* __restrict__ wp,
                         float* __restrict__ out) {
  __shared__ __align__(16) _Float16 hT[3][64];     // rows 0,1 = h; row 2 = zeros
  __shared__ __align__(16) _Float16 xT[2][3][64];  // dbuf; row 2 zeros; dims>=46 zero
  __shared__ float hfin[2][HH];
  __shared__ float lg[2][CC];

  const int l   = threadIdx.x;
  const int m16 = l & 15;
  const int kg  = l >> 4;
  const int us  = 16 * kg + m16;                    // unit owned by this lane
  const int rs  = ((m16 & 3) < 2) ? (m16 & 1) : 2;  // A-frag row select
  const int p0  = 2 * blockIdx.x;

  // zero LDS (single wave -> ordered by later lgkmcnt)
  hT[0][l] = (_Float16)0.f; hT[1][l] = (_Float16)0.f; hT[2][l] = (_Float16)0.f;
  xT[0][0][l] = (_Float16)0.f; xT[0][1][l] = (_Float16)0.f; xT[0][2][l] = (_Float16)0.f;
  xT[1][0][l] = (_Float16)0.f; xT[1][1][l] = (_Float16)0.f; xT[1][2][l] = (_Float16)0.f;

  const float br  = b_ih[us] + b_hh[us];
  const float bz  = b_ih[64 + us] + b_hh[64 + us];
  const float bnx = b_ih[128 + us];
  const float bnh = b_hh[128 + us];

  // persistent B-fragments: 16 tiles (r,z fused K=128; nh,nx K=64 each)
  half8 wr[4][4], wz[4][4], wnh[4][2], wnx[4][2];
#pragma unroll
  for (int g = 0; g < 4; ++g) {
    const _Float16* rowr = wp + (size_t)(16 * g + m16) * KP + 8 * kg;
    const _Float16* rowz = wp + (size_t)(64 + 16 * g + m16) * KP + 8 * kg;
    const _Float16* rown = wp + (size_t)(128 + 16 * g + m16) * KP + 8 * kg;
#pragma unroll
    for (int s = 0; s < 4; ++s) {
      wr[g][s] = *(const half8*)(rowr + 32 * s);
      wz[g][s] = *(const half8*)(rowz + 32 * s);
    }
    wnh[g][0] = *(const half8*)(rown);
    wnh[g][1] = *(const half8*)(rown + 32);
    wnx[g][0] = *(const half8*)(rown + 64);
    wnx[g][1] = *(const half8*)(rown + 96);
  }

  // x: lane i<46 owns dim i of both rows
  const bool lv = (l < II);
  const float* xb0 = x + (size_t)p0 * TT * II + (lv ? l : 0);
  const float* xb1 = x + (size_t)(p0 + 1) * TT * II + (lv ? l : 0);

  float x0a = lv ? xb0[0] : 0.f,        x0b = lv ? xb1[0] : 0.f;
  float x1a = lv ? xb0[II] : 0.f,       x1b = lv ? xb1[II] : 0.f;
  float xc0 = lv ? xb0[2 * II] : 0.f,   xc1 = lv ? xb1[2 * II] : 0.f;
  float xn0 = lv ? xb0[3 * II] : 0.f,   xn1 = lv ? xb1[3 * II] : 0.f;

  if (lv) {
    xT[0][0][l] = (_Float16)x0a; xT[0][1][l] = (_Float16)x0b;
    xT[1][0][l] = (_Float16)x1a; xT[1][1][l] = (_Float16)x1b;
  }
  asm volatile("s_waitcnt lgkmcnt(0)" ::: "memory");

  half8 axc0 = *(const half8*)&xT[0][rs][8 * kg];
  half8 axc1 = *(const half8*)&xT[0][rs][32 + 8 * kg];

  float h0 = 0.f, h1 = 0.f;
  const float4v zero4 = {0.f, 0.f, 0.f, 0.f};

  for (int t = 0; t < TT; ++t) {
    // h A-frags (written last iter; drained by loop-end lgkmcnt)
    half8 a0 = *(const half8*)&hT[rs][8 * kg];
    half8 a1 = *(const half8*)&hT[rs][32 + 8 * kg];

    float4v accr[4], accz[4], accnh[4], accnx[4];
    // x-part first (operands ready since last iter; fills a0/a1 latency)
#pragma unroll
    for (int g = 0; g < 4; ++g) {
      accr[g]  = __builtin_amdgcn_mfma_f32_16x16x32_f16(axc0, wr[g][2], zero4, 0, 0, 0);
      accz[g]  = __builtin_amdgcn_mfma_f32_16x16x32_f16(axc0, wz[g][2], zero4, 0, 0, 0);
      accnx[g] = __builtin_amdgcn_mfma_f32_16x16x32_f16(axc0, wnx[g][0], zero4, 0, 0, 0);
    }
#pragma unroll
    for (int g = 0; g < 4; ++g) {
      accr[g]  = __builtin_amdgcn_mfma_f32_16x16x32_f16(axc1, wr[g][3], accr[g], 0, 0, 0);
      accz[g]  = __builtin_amdgcn_mfma_f32_16x16x32_f16(axc1, wz[g][3], accz[g], 0, 0, 0);
      accnx[g] = __builtin_amdgcn_mfma_f32_16x16x32_f16(axc1, wnx[g][1], accnx[g], 0, 0, 0);
    }
    // h-part (critical chain)
#pragma unroll
    for (int g = 0; g < 4; ++g) {
      accr[g]  = __builtin_amdgcn_mfma_f32_16x16x32_f16(a0, wr[g][0], accr[g], 0, 0, 0);
      accz[g]  = __builtin_amdgcn_mfma_f32_16x16x32_f16(a0, wz[g][0], accz[g], 0, 0, 0);
      accnh[g] = __builtin_amdgcn_mfma_f32_16x16x32_f16(a0, wnh[g][0], zero4, 0, 0, 0);
    }
#pragma unroll
    for (int g = 0; g < 4; ++g) {
      accr[g]  = __builtin_amdgcn_mfma_f32_16x16x32_f16(a1, wr[g][1], accr[g], 0, 0, 0);
      accz[g]  = __builtin_amdgcn_mfma_f32_16x16x32_f16(a1, wz[g][1], accz[g], 0, 0, 0);
      accnh[g] = __builtin_amdgcn_mfma_f32_16x16x32_f16(a1, wnh[g][1], accnh[g], 0, 0, 0);
    }

    // ---- off-chain: stage x(t+2), prefetch x(t+4), read x-frags for t+1 ----
    if (lv && t + 2 < TT) {
      xT[(t + 2) & 1][0][l] = (_Float16)xc0;
      xT[(t + 2) & 1][1][l] = (_Float16)xc1;
    }
    xc0 = xn0; xc1 = xn1;
    if (lv && t + 4 < TT) {
      xn0 = xb0[(size_t)(t + 4) * II];
      xn1 = xb1[(size_t)(t + 4) * II];
    }
    half8 nxa0 = axc0, nxa1 = axc1;
    if (t + 1 < TT) {
      nxa0 = *(const half8*)&xT[(t + 1) & 1][rs][8 * kg];
      nxa1 = *(const half8*)&xT[(t + 1) & 1][rs][32 + 8 * kg];
    }

    // kg-select: this lane's unit us = 16*kg + m16 (constant-index ternaries)
    float rA0  = kg==0?accr[0][0] : kg==1?accr[1][0] : kg==2?accr[2][0] : accr[3][0];
    float rA1  = kg==0?accr[0][1] : kg==1?accr[1][1] : kg==2?accr[2][1] : accr[3][1];
    float zA0  = kg==0?accz[0][0] : kg==1?accz[1][0] : kg==2?accz[2][0] : accz[3][0];
    float zA1  = kg==0?accz[0][1] : kg==1?accz[1][1] : kg==2?accz[2][1] : accz[3][1];
    float nhA0 = kg==0?accnh[0][0]: kg==1?accnh[1][0]: kg==2?accnh[2][0]: accnh[3][0];
    float nhA1 = kg==0?accnh[0][1]: kg==1?accnh[1][1]: kg==2?accnh[2][1]: accnh[3][1];
    float nxA0 = kg==0?accnx[0][0]: kg==1?accnx[1][0]: kg==2?accnx[2][0]: accnx[3][0];
    float nxA1 = kg==0?accnx[0][1]: kg==1?accnx[1][1]: kg==2?accnx[2][1]: accnx[3][1];

    // gates (2 sets/lane)
    float rg0 = fsigm(rA0 + br);
    float rg1 = fsigm(rA1 + br);
    float zg0 = fsigm(zA0 + bz);
    float zg1 = fsigm(zA1 + bz);
    float ng0 = ftanh2(__builtin_fmaf(rg0, nhA0 + bnh, nxA0 + bnx));
    float ng1 = ftanh2(__builtin_fmaf(rg1, nhA1 + bnh, nxA1 + bnx));
    h0 = __builtin_fmaf(zg0, h0 - ng0, ng0);
    h1 = __builtin_fmaf(zg1, h1 - ng1, ng1);

    hT[0][us] = (_Float16)h0;
    hT[1][us] = (_Float16)h1;
    axc0 = nxa0; axc1 = nxa1;
    asm volatile("s_waitcnt lgkmcnt(0)" ::: "memory");  // h visible to all lanes
  }

  // ================= Epilogue: FC + softmax (per-wave, 2 rows) =================
  hfin[0][us] = h0;
  hfin[1][us] = h1;
  asm volatile("s_waitcnt lgkmcnt(0)" ::: "memory");
  if (l < 2 * CC) {
    int row = l >> 3, c = l & 7;
    float acc = fc_b[c];
#pragma unroll
    for (int j = 0; j < HH; ++j) acc += hfin[row][j] * fc_w[c * HH + j];
    lg[row][c] = acc;
  }
  asm volatile("s_waitcnt lgkmcnt(0)" ::: "memory");
  if (l < 2 * CC) {
    int row = l >> 3, c = l & 7;
    float mx = lg[row][0];
#pragma unroll
    for (int j = 1; j < CC; ++j) mx = fmaxf(mx, lg[row][j]);
    float ssum = 0.f;
#pragma unroll
    for (int j = 0; j < CC; ++j) ssum += __expf(lg[row][j] - mx);
    out[(size_t)(p0 + row) * CC + c] = __expf(lg[row][c] - mx) / ssum;
  }
}

extern "C" void kernel_launch(void* const* d_in, const int* in_sizes, int n_in,
                              void* d_out, int out_size, void* d_ws, size_t ws_size,
                              hipStream_t stream) {
  const float* x    = (const float*)d_in[0];
  const float* w_ih = (const float*)d_in[1];
  const float* w_hh = (const float*)d_in[2];
  const float* b_ih = (const float*)d_in[3];
  const float* b_hh = (const float*)d_in[4];
  const float* fc_w = (const float*)d_in[5];
  const float* fc_b = (const float*)d_in[6];

  _Float16* wp = (_Float16*)d_ws;  // 192*128 f16 = 48 KiB

  pack_w<<<96, 256, 0, stream>>>(w_ih, w_hh, wp);
  gru_main<<<1024, 64, 0, stream>>>(x, b_ih, b_hh, fc_w, fc_b, wp, (float*)d_out);
}

// Round 9
// 214.856 us; speedup vs baseline: 1.8372x; 1.8372x over previous
//
#include <hip/hip_runtime.h>
#include <hip/hip_bf16.h>

#define TT 512
#define II 46
#define HH 64
#define GG 192
#define CC 8
#define RR 8     // rows per block
#define KP 128   // fused K per gate: [h (64) | x (46, zero-padded to 64)]

typedef __attribute__((ext_vector_type(8))) _Float16 half8;
typedef __attribute__((ext_vector_type(4))) float float4v;

__device__ inline float fsigm(float xv) {
  return __builtin_amdgcn_rcpf(1.f + __expf(-xv));
}
// tanh(x) = 1 - 2/(1 + e^{2x}); saturates correctly at +-1, branch-free
__device__ inline float ftanh2(float xv) {
  float e = __expf(2.f * xv);
  return __builtin_fmaf(-2.f, __builtin_amdgcn_rcpf(1.f + e), 1.f);
}

// Barrier WITHOUT vmcnt drain: LDS ops fenced (lgkmcnt(0)); global x prefetches
// keep riding across (consumed 2+ steps later).
__device__ inline void barrier_lds_only() {
  asm volatile("s_waitcnt lgkmcnt(0)" ::: "memory");
  __builtin_amdgcn_s_barrier();
  asm volatile("" ::: "memory");
}

// wp[u][k] f16, u in [0,192): k<64 -> w_hh[u][k]; 64<=k<110 -> w_ih[u][k-64]; else 0.
__global__ void pack_w(const float* __restrict__ w_ih, const float* __restrict__ w_hh,
                       _Float16* __restrict__ wp) {
  int idx = blockIdx.x * 256 + threadIdx.x;  // 192*128 = 24576 exact
  int u = idx >> 7, k = idx & 127;
  float v = (k < HH) ? w_hh[u * HH + k]
                     : ((k < HH + II) ? w_ih[u * II + (k - HH)] : 0.f);
  wp[idx] = (_Float16)v;
}

// Frag layout (f16): element (M-row m, k) at [k>>5][((k>>3)&3)*16 + m][k&7];
// lane l reads kstep s as frag[s][l][0..7] (m = l&15, k = 32s + (l>>4)*8 + j).
// Batch row b (0..7) at M-row (b>>1)*4 + (b&1) -> rows {0,1,4,5,8,9,12,13};
// lane (kg,m16)'s acc elems e=0,1 are then batch rows {2kg, 2kg+1}. No shuffles.
// hsf: fused k 0..63 (h), double-buffered. xsf: x part, TRIPLE-buffered so the
// x-fragments for step t+1 are readable PRE-barrier during step t (staged at
// t-1, fenced by the t barrier; next overwrite at t+2 is 2 barriers away).
__launch_bounds__(256, 1)
__global__ void gru_main(const float* __restrict__ x,
                         const float* __restrict__ b_ih, const float* __restrict__ b_hh,
                         const float* __restrict__ fc_w, const float* __restrict__ fc_b,
                         const _Float16* __restrict__ wp,
                         float* __restrict__ out) {
  __shared__ __align__(16) _Float16 hsf[2][2][64][8];
  __shared__ __align__(16) _Float16 xsf[3][2][64][8];
  __shared__ float hf[RR][HH + 1];
  __shared__ float fcw[CC * HH];
  __shared__ float fcbs[CC];
  __shared__ float lgts[RR][CC];

  const int tau = threadIdx.x;
  const int w4  = tau >> 6;   // wave 0..3 (units 16*w4 .. 16*w4+15)
  const int l   = tau & 63;
  const int m16 = l & 15;
  const int kg  = l >> 4;
  const int row0 = blockIdx.x * RR;

  {
    _Float16* p = &hsf[0][0][0][0];
    for (int i = tau; i < 2 * 2 * 64 * 8; i += 256) p[i] = (_Float16)0.f;
    p = &xsf[0][0][0][0];
    for (int i = tau; i < 3 * 2 * 64 * 8; i += 256) p[i] = (_Float16)0.f;
  }

  const int u = 16 * w4 + m16;   // gate unit (output col) owned by this lane
  const float br  = b_ih[u] + b_hh[u];
  const float bz  = b_ih[64 + u] + b_hh[64 + u];
  const float bnx = b_ih[128 + u];
  const float bnh = b_hh[128 + u];

  // persistent B-fragments: h-part ksteps (k 0..63) and x-part ksteps (k 64..127)
  half8 bhr[2], bhz[2], bhn[2], bxr[2], bxz[2], bxn[2];
  {
    const _Float16* rr = wp + (size_t)u * KP + 8 * kg;
    const _Float16* rz = wp + (size_t)(64 + u) * KP + 8 * kg;
    const _Float16* rn = wp + (size_t)(128 + u) * KP + 8 * kg;
    bhr[0] = *(const half8*)(rr);      bhr[1] = *(const half8*)(rr + 32);
    bxr[0] = *(const half8*)(rr + 64); bxr[1] = *(const half8*)(rr + 96);
    bhz[0] = *(const half8*)(rz);      bhz[1] = *(const half8*)(rz + 32);
    bxz[0] = *(const half8*)(rz + 64); bxz[1] = *(const half8*)(rz + 96);
    bhn[0] = *(const half8*)(rn);      bhn[1] = *(const half8*)(rn + 32);
    bxn[0] = *(const half8*)(rn + 64); bxn[1] = *(const half8*)(rn + 96);
  }

  // h write-back coords: h[b=2kg+i] at frag (m = 4kg+i, k = u)
  const int sh  = w4 >> 1;
  const int kgp = (u >> 3) & 3;
  const int jp  = u & 7;

  // x staging: thread owns elements tau and tau+256 of the 8x46 slab (368 total)
  const int r1 = tau / II, i1 = tau % II;
  const int m1 = (r1 >> 1) * 4 + (r1 & 1);
  const bool has2 = (tau + 256) < RR * II;
  const int e2 = tau + 256;
  const int r2 = has2 ? e2 / II : r1, i2 = has2 ? e2 % II : i1;
  const int m2 = (r2 >> 1) * 4 + (r2 & 1);
  const float* xp1 = x + (size_t)(row0 + r1) * TT * II + i1;
  const float* xp2 = x + (size_t)(row0 + r2) * TT * II + i2;
  const int s1 = i1 >> 5, kg1 = (i1 >> 3) & 3, j1 = i1 & 7;
  const int s2 = i2 >> 5, kg2 = (i2 >> 3) & 3, j2 = i2 & 7;

  auto stageX = [&](int buf, float va, float vb) {
    xsf[buf][s1][kg1 * 16 + m1][j1] = (_Float16)va;
    if (has2) xsf[buf][s2][kg2 * 16 + m2][j2] = (_Float16)vb;
  };

  float hreg[2] = {0.f, 0.f};

  // prologue: x(0)->buf0, x(1)->buf1; xc=x(2), xn=x(3)
  float v0a = xp1[0],            v0b = has2 ? xp2[0] : 0.f;
  float v1a = xp1[II],           v1b = has2 ? xp2[II] : 0.f;
  float xc1 = xp1[2 * II],       xc2 = has2 ? xp2[2 * II] : 0.f;
  float xn1 = xp1[3 * II],       xn2 = has2 ? xp2[3 * II] : 0.f;
  __syncthreads();               // zero-init fence
  stageX(0, v0a, v0b);
  stageX(1, v1a, v1b);
  __syncthreads();               // prologue staging fence

  // x-part pre-activations (incl. biases) for t=0 from buf0
  float4v xrA = {br, br, br, br};
  float4v xzA = {bz, bz, bz, bz};
  float4v xnA = {bnx, bnx, bnx, bnx};
  {
    half8 c0 = *(const half8*)&xsf[0][0][l][0];
    half8 c1 = *(const half8*)&xsf[0][1][l][0];
    xrA = __builtin_amdgcn_mfma_f32_16x16x32_f16(c0, bxr[0], xrA, 0, 0, 0);
    xzA = __builtin_amdgcn_mfma_f32_16x16x32_f16(c0, bxz[0], xzA, 0, 0, 0);
    xnA = __builtin_amdgcn_mfma_f32_16x16x32_f16(c0, bxn[0], xnA, 0, 0, 0);
    xrA = __builtin_amdgcn_mfma_f32_16x16x32_f16(c1, bxr[1], xrA, 0, 0, 0);
    xzA = __builtin_amdgcn_mfma_f32_16x16x32_f16(c1, bxz[1], xzA, 0, 0, 0);
    xnA = __builtin_amdgcn_mfma_f32_16x16x32_f16(c1, bxn[1], xnA, 0, 0, 0);
  }
  float4v xrB, xzB, xnB;

  // One iteration. xC = x-part accs for step t (ready); xN = accs for t+1
  // (computed here, pre-barrier).
  auto iter = [&](int t, float4v& xrC, float4v& xzC, float4v& xnC,
                  float4v& xrN, float4v& xzN, float4v& xnN) {
    // ---- pre-barrier: stage x(t+2), prefetch x(t+4), compute x-part(t+1) ----
    if (t + 2 < TT) stageX((t + 2) % 3, xc1, xc2);
    xc1 = xn1; xc2 = xn2;
    if (t + 4 < TT) {
      xn1 = xp1[(size_t)(t + 4) * II];
      if (has2) xn2 = xp2[(size_t)(t + 4) * II];
    }
    if (t + 1 < TT) {
      const int nb = (t + 1) % 3;
      half8 c0 = *(const half8*)&xsf[nb][0][l][0];
      half8 c1 = *(const half8*)&xsf[nb][1][l][0];
      xrN = (float4v){br, br, br, br};
      xzN = (float4v){bz, bz, bz, bz};
      xnN = (float4v){bnx, bnx, bnx, bnx};
      xrN = __builtin_amdgcn_mfma_f32_16x16x32_f16(c0, bxr[0], xrN, 0, 0, 0);
      xzN = __builtin_amdgcn_mfma_f32_16x16x32_f16(c0, bxz[0], xzN, 0, 0, 0);
      xnN = __builtin_amdgcn_mfma_f32_16x16x32_f16(c0, bxn[0], xnN, 0, 0, 0);
      xrN = __builtin_amdgcn_mfma_f32_16x16x32_f16(c1, bxr[1], xrN, 0, 0, 0);
      xzN = __builtin_amdgcn_mfma_f32_16x16x32_f16(c1, bxz[1], xzN, 0, 0, 0);
      xnN = __builtin_amdgcn_mfma_f32_16x16x32_f16(c1, bxn[1], xnN, 0, 0, 0);
    }
    __builtin_amdgcn_sched_barrier(0);  // pin x-MFMAs before the barrier
    barrier_lds_only();                 // hsf[cur] (h(t)) now visible

    // ---- critical chain: h-GEMM (C-init = x-part + biases) + gates ----
    const int cur = t & 1, nxt = cur ^ 1;
    half8 a0 = *(const half8*)&hsf[cur][0][l][0];
    half8 a1 = *(const half8*)&hsf[cur][1][l][0];
    float4v nh4 = {bnh, bnh, bnh, bnh};
    float4v accr  = __builtin_amdgcn_mfma_f32_16x16x32_f16(a0, bhr[0], xrC, 0, 0, 0);
    float4v accz  = __builtin_amdgcn_mfma_f32_16x16x32_f16(a0, bhz[0], xzC, 0, 0, 0);
    float4v accnh = __builtin_amdgcn_mfma_f32_16x16x32_f16(a0, bhn[0], nh4, 0, 0, 0);
    accr  = __builtin_amdgcn_mfma_f32_16x16x32_f16(a1, bhr[1], accr, 0, 0, 0);
    accz  = __builtin_amdgcn_mfma_f32_16x16x32_f16(a1, bhz[1], accz, 0, 0, 0);
    accnh = __builtin_amdgcn_mfma_f32_16x16x32_f16(a1, bhn[1], accnh, 0, 0, 0);

#pragma unroll
    for (int i = 0; i < 2; ++i) {
      float rg = fsigm(accr[i]);
      float zg = fsigm(accz[i]);
      float pre = __builtin_fmaf(rg, accnh[i], xnC[i]);
      float ng = ftanh2(pre);
      hreg[i] = __builtin_fmaf(zg, hreg[i] - ng, ng);
      hsf[nxt][sh][kgp * 16 + kg * 4 + i][jp] = (_Float16)hreg[i];
    }
  };

  for (int t = 0; t < TT; t += 2) {
    iter(t,     xrA, xzA, xnA, xrB, xzB, xnB);
    iter(t + 1, xrB, xzB, xnB, xrA, xzA, xnA);
  }

  // ================= Epilogue: FC + softmax =================
  hf[2 * kg + 0][u] = hreg[0];
  hf[2 * kg + 1][u] = hreg[1];
  fcw[tau] = fc_w[tau];
  fcw[tau + 256] = fc_w[tau + 256];
  if (tau < CC) fcbs[tau] = fc_b[tau];
  __syncthreads();
  if (tau < RR * CC) {
    int rr = tau >> 3, c = tau & 7;
    float acc = fcbs[c];
#pragma unroll
    for (int j = 0; j < HH; ++j) acc += hf[rr][j] * fcw[c * HH + j];
    lgts[rr][c] = acc;
  }
  __syncthreads();
  if (tau < RR * CC) {
    int rr = tau >> 3, c = tau & 7;
    float mx = lgts[rr][0];
#pragma unroll
    for (int j = 1; j < CC; ++j) mx = fmaxf(mx, lgts[rr][j]);
    float ssum = 0.f;
#pragma unroll
    for (int j = 0; j < CC; ++j) ssum += __expf(lgts[rr][j] - mx);
    out[(size_t)(row0 + rr) * CC + c] = __expf(lgts[rr][c] - mx) / ssum;
  }
}

extern "C" void kernel_launch(void* const* d_in, const int* in_sizes, int n_in,
                              void* d_out, int out_size, void* d_ws, size_t ws_size,
                              hipStream_t stream) {
  const float* x    = (const float*)d_in[0];
  const float* w_ih = (const float*)d_in[1];
  const float* w_hh = (const float*)d_in[2];
  const float* b_ih = (const float*)d_in[3];
  const float* b_hh = (const float*)d_in[4];
  const float* fc_w = (const float*)d_in[5];
  const float* fc_b = (const float*)d_in[6];

  _Float16* wp = (_Float16*)d_ws;  // 192*128 f16 = 48 KiB

  pack_w<<<96, 256, 0, stream>>>(w_ih, w_hh, wp);
  gru_main<<<256, 256, 0, stream>>>(x, b_ih, b_hh, fc_w, fc_b, wp, (float*)d_out);
}

// Round 10
// 191.148 us; speedup vs baseline: 2.0651x; 1.1240x over previous
//
#include <hip/hip_runtime.h>
#include <hip/hip_bf16.h>

#define TT 512
#define II 46
#define HH 64
#define GG 192
#define CC 8
#define RR 8     // rows per block
#define KP 128   // fused K per gate: [h (64) | x (46, zero-padded to 64)]

typedef __attribute__((ext_vector_type(8))) _Float16 half8;
typedef __attribute__((ext_vector_type(4))) float float4v;

__device__ inline float fsigm(float xv) {
  return __builtin_amdgcn_rcpf(1.f + __expf(-xv));
}
// tanh(x) = 1 - 2/(1 + e^{2x}); saturates correctly at +-1, branch-free
__device__ inline float ftanh2(float xv) {
  float e = __expf(2.f * xv);
  return __builtin_fmaf(-2.f, __builtin_amdgcn_rcpf(1.f + e), 1.f);
}

// Barrier WITHOUT vmcnt drain: LDS ops fenced (lgkmcnt(0)); global x prefetches
// keep riding across (consumed 2+ steps later).
__device__ inline void barrier_lds_only() {
  asm volatile("s_waitcnt lgkmcnt(0)" ::: "memory");
  __builtin_amdgcn_s_barrier();
  asm volatile("" ::: "memory");
}

// wp[u][k] f16, u in [0,192): k<64 -> w_hh[u][k]; 64<=k<110 -> w_ih[u][k-64]; else 0.
__global__ void pack_w(const float* __restrict__ w_ih, const float* __restrict__ w_hh,
                       _Float16* __restrict__ wp) {
  int idx = blockIdx.x * 256 + threadIdx.x;  // 192*128 = 24576 exact
  int u = idx >> 7, k = idx & 127;
  float v = (k < HH) ? w_hh[u * HH + k]
                     : ((k < HH + II) ? w_ih[u * II + (k - HH)] : 0.f);
  wp[idx] = (_Float16)v;
}

// Frag layout (f16): element (M-row m, k) at [k>>5][((k>>3)&3)*16 + m][k&7];
// lane l reads kstep s as frag[s][l][0..7] (m = l&15, k = 32s + (l>>4)*8 + j).
// Batch row b (0..7) at M-row (b>>1)*4 + (b&1) -> rows {0,1,4,5,8,9,12,13};
// lane (kg,m16)'s acc elems e=0,1 are then batch rows {2kg, 2kg+1}. No shuffles.
// hsf: h, double-buffered (t&1). xsf: x part, 4 buffers (t&3) so step t can read
// x(t+1)'s fragments RIGHT AFTER its barrier (staged at end of step t-1) with
// all indices compile-time static via unroll-by-4.
__launch_bounds__(256, 1)
__global__ void gru_main(const float* __restrict__ x,
                         const float* __restrict__ b_ih, const float* __restrict__ b_hh,
                         const float* __restrict__ fc_w, const float* __restrict__ fc_b,
                         const _Float16* __restrict__ wp,
                         float* __restrict__ out) {
  __shared__ __align__(16) _Float16 hsf[2][2][64][8];
  __shared__ __align__(16) _Float16 xsf[4][2][64][8];
  __shared__ float hf[RR][HH + 1];
  __shared__ float fcw[CC * HH];
  __shared__ float fcbs[CC];
  __shared__ float lgts[RR][CC];

  const int tau = threadIdx.x;
  const int w4  = tau >> 6;   // wave 0..3 (units 16*w4 .. 16*w4+15)
  const int l   = tau & 63;
  const int m16 = l & 15;
  const int kg  = l >> 4;
  const int row0 = blockIdx.x * RR;

  {
    _Float16* p = &hsf[0][0][0][0];
    for (int i = tau; i < 2 * 2 * 64 * 8; i += 256) p[i] = (_Float16)0.f;
    p = &xsf[0][0][0][0];
    for (int i = tau; i < 4 * 2 * 64 * 8; i += 256) p[i] = (_Float16)0.f;
  }

  const int u = 16 * w4 + m16;   // gate unit (output col) owned by this lane
  const float br  = b_ih[u] + b_hh[u];
  const float bz  = b_ih[64 + u] + b_hh[64 + u];
  const float bnx = b_ih[128 + u];
  const float bnh = b_hh[128 + u];

  // persistent B-fragments: h-part ksteps (k 0..63) and x-part ksteps (k 64..127)
  half8 bhr[2], bhz[2], bhn[2], bxr[2], bxz[2], bxn[2];
  {
    const _Float16* rr = wp + (size_t)u * KP + 8 * kg;
    const _Float16* rz = wp + (size_t)(64 + u) * KP + 8 * kg;
    const _Float16* rn = wp + (size_t)(128 + u) * KP + 8 * kg;
    bhr[0] = *(const half8*)(rr);      bhr[1] = *(const half8*)(rr + 32);
    bxr[0] = *(const half8*)(rr + 64); bxr[1] = *(const half8*)(rr + 96);
    bhz[0] = *(const half8*)(rz);      bhz[1] = *(const half8*)(rz + 32);
    bxz[0] = *(const half8*)(rz + 64); bxz[1] = *(const half8*)(rz + 96);
    bhn[0] = *(const half8*)(rn);      bhn[1] = *(const half8*)(rn + 32);
    bxn[0] = *(const half8*)(rn + 64); bxn[1] = *(const half8*)(rn + 96);
  }

  // h write-back coords: h[b=2kg+i] at frag (m = 4kg+i, k = u)
  const int sh  = w4 >> 1;
  const int kgp = (u >> 3) & 3;
  const int jp  = u & 7;

  // x staging: thread owns elements tau and tau+256 of the 8x46 slab (368 total)
  const int r1 = tau / II, i1 = tau % II;
  const int m1 = (r1 >> 1) * 4 + (r1 & 1);
  const bool has2 = (tau + 256) < RR * II;
  const int e2 = tau + 256;
  const int r2 = has2 ? e2 / II : r1, i2 = has2 ? e2 % II : i1;
  const int m2 = (r2 >> 1) * 4 + (r2 & 1);
  const float* xp1 = x + (size_t)(row0 + r1) * TT * II + i1;
  const float* xp2 = x + (size_t)(row0 + r2) * TT * II + i2;
  const int s1 = i1 >> 5, kg1 = (i1 >> 3) & 3, j1 = i1 & 7;
  const int s2 = i2 >> 5, kg2 = (i2 >> 3) & 3, j2 = i2 & 7;

  auto stageX = [&](int buf, float va, float vb) {
    xsf[buf][s1][kg1 * 16 + m1][j1] = (_Float16)va;
    if (has2) xsf[buf][s2][kg2 * 16 + m2][j2] = (_Float16)vb;
  };

  float hreg[2] = {0.f, 0.f};

  // prologue: x(0)->buf0, x(1)->buf1; xc=x(2), xn=x(3)
  float v0a = xp1[0],            v0b = has2 ? xp2[0] : 0.f;
  float v1a = xp1[II],           v1b = has2 ? xp2[II] : 0.f;
  float xc1 = xp1[2 * II],       xc2 = has2 ? xp2[2 * II] : 0.f;
  float xn1 = xp1[3 * II],       xn2 = has2 ? xp2[3 * II] : 0.f;
  __syncthreads();               // zero-init fence
  stageX(0, v0a, v0b);
  stageX(1, v1a, v1b);
  __syncthreads();               // prologue staging fence

  // x-part pre-activations (incl. biases) for t=0 from buf0
  float4v xrA = {br, br, br, br};
  float4v xzA = {bz, bz, bz, bz};
  float4v xnA = {bnx, bnx, bnx, bnx};
  {
    half8 c0 = *(const half8*)&xsf[0][0][l][0];
    half8 c1 = *(const half8*)&xsf[0][1][l][0];
    xrA = __builtin_amdgcn_mfma_f32_16x16x32_f16(c0, bxr[0], xrA, 0, 0, 0);
    xzA = __builtin_amdgcn_mfma_f32_16x16x32_f16(c0, bxz[0], xzA, 0, 0, 0);
    xnA = __builtin_amdgcn_mfma_f32_16x16x32_f16(c0, bxn[0], xnA, 0, 0, 0);
    xrA = __builtin_amdgcn_mfma_f32_16x16x32_f16(c1, bxr[1], xrA, 0, 0, 0);
    xzA = __builtin_amdgcn_mfma_f32_16x16x32_f16(c1, bxz[1], xzA, 0, 0, 0);
    xnA = __builtin_amdgcn_mfma_f32_16x16x32_f16(c1, bxn[1], xnA, 0, 0, 0);
  }
  float4v xrB, xzB, xnB;

  // One step. cur/nb/sb are compile-time constants (unroll-by-4).
  // xC = x-part accs for step t (ready); xN = x-part accs for t+1 (made here).
  auto iter = [&](int t, int cur, int nb, int sb,
                  float4v& xrC, float4v& xzC, float4v& xnC,
                  float4v& xrN, float4v& xzN, float4v& xnN) {
    barrier_lds_only();          // h(t) in hsf[cur]; x(t+1) in xsf[nb] visible
    const int nxt = cur ^ 1;
    // ALL LDS reads issued back-to-back: one pipelined latency wall (~130 cyc)
    half8 a0 = *(const half8*)&hsf[cur][0][l][0];
    half8 a1 = *(const half8*)&hsf[cur][1][l][0];
    half8 c0 = *(const half8*)&xsf[nb][0][l][0];
    half8 c1 = *(const half8*)&xsf[nb][1][l][0];

    // critical: h-GEMM, C-init = x-part accs (biases included)
    float4v nh4 = {bnh, bnh, bnh, bnh};
    float4v accr  = __builtin_amdgcn_mfma_f32_16x16x32_f16(a0, bhr[0], xrC, 0, 0, 0);
    float4v accz  = __builtin_amdgcn_mfma_f32_16x16x32_f16(a0, bhz[0], xzC, 0, 0, 0);
    float4v accnh = __builtin_amdgcn_mfma_f32_16x16x32_f16(a0, bhn[0], nh4, 0, 0, 0);
    accr  = __builtin_amdgcn_mfma_f32_16x16x32_f16(a1, bhr[1], accr, 0, 0, 0);
    accz  = __builtin_amdgcn_mfma_f32_16x16x32_f16(a1, bhz[1], accz, 0, 0, 0);
    accnh = __builtin_amdgcn_mfma_f32_16x16x32_f16(a1, bhn[1], accnh, 0, 0, 0);

    // off-critical: x-part for t+1 (consumed next step; latency hides under gates)
    xrN = (float4v){br, br, br, br};
    xzN = (float4v){bz, bz, bz, bz};
    xnN = (float4v){bnx, bnx, bnx, bnx};
    xrN = __builtin_amdgcn_mfma_f32_16x16x32_f16(c0, bxr[0], xrN, 0, 0, 0);
    xzN = __builtin_amdgcn_mfma_f32_16x16x32_f16(c0, bxz[0], xzN, 0, 0, 0);
    xnN = __builtin_amdgcn_mfma_f32_16x16x32_f16(c0, bxn[0], xnN, 0, 0, 0);
    xrN = __builtin_amdgcn_mfma_f32_16x16x32_f16(c1, bxr[1], xrN, 0, 0, 0);
    xzN = __builtin_amdgcn_mfma_f32_16x16x32_f16(c1, bxz[1], xzN, 0, 0, 0);
    xnN = __builtin_amdgcn_mfma_f32_16x16x32_f16(c1, bxn[1], xnN, 0, 0, 0);

    // gates (critical; x-MFMA latency drains during the exp chains)
#pragma unroll
    for (int i = 0; i < 2; ++i) {
      float rg = fsigm(accr[i]);
      float zg = fsigm(accz[i]);
      float pre = __builtin_fmaf(rg, accnh[i], xnC[i]);
      float ng = ftanh2(pre);
      hreg[i] = __builtin_fmaf(zg, hreg[i] - ng, ng);
      hsf[nxt][sh][kgp * 16 + kg * 4 + i][jp] = (_Float16)hreg[i];
    }

    // staging for x(t+2) + global prefetch x(t+4) (off-critical, before barrier)
    stageX(sb, xc1, xc2);
    xc1 = xn1; xc2 = xn2;
    if (t + 4 < TT) {
      xn1 = xp1[(size_t)(t + 4) * II];
      if (has2) xn2 = xp2[(size_t)(t + 4) * II];
    }
  };

  for (int t = 0; t < TT; t += 4) {
    iter(t,     0, 1, 2, xrA, xzA, xnA, xrB, xzB, xnB);
    iter(t + 1, 1, 2, 3, xrB, xzB, xnB, xrA, xzA, xnA);
    iter(t + 2, 0, 3, 0, xrA, xzA, xnA, xrB, xzB, xnB);
    iter(t + 3, 1, 0, 1, xrB, xzB, xnB, xrA, xzA, xnA);
  }

  // ================= Epilogue: FC + softmax =================
  hf[2 * kg + 0][u] = hreg[0];
  hf[2 * kg + 1][u] = hreg[1];
  fcw[tau] = fc_w[tau];
  fcw[tau + 256] = fc_w[tau + 256];
  if (tau < CC) fcbs[tau] = fc_b[tau];
  __syncthreads();
  if (tau < RR * CC) {
    int rr = tau >> 3, c = tau & 7;
    float acc = fcbs[c];
#pragma unroll
    for (int j = 0; j < HH; ++j) acc += hf[rr][j] * fcw[c * HH + j];
    lgts[rr][c] = acc;
  }
  __syncthreads();
  if (tau < RR * CC) {
    int rr = tau >> 3, c = tau & 7;
    float mx = lgts[rr][0];
#pragma unroll
    for (int j = 1; j < CC; ++j) mx = fmaxf(mx, lgts[rr][j]);
    float ssum = 0.f;
#pragma unroll
    for (int j = 0; j < CC; ++j) ssum += __expf(lgts[rr][j] - mx);
    out[(size_t)(row0 + rr) * CC + c] = __expf(lgts[rr][c] - mx) / ssum;
  }
}

extern "C" void kernel_launch(void* const* d_in, const int* in_sizes, int n_in,
                              void* d_out, int out_size, void* d_ws, size_t ws_size,
                              hipStream_t stream) {
  const float* x    = (const float*)d_in[0];
  const float* w_ih = (const float*)d_in[1];
  const float* w_hh = (const float*)d_in[2];
  const float* b_ih = (const float*)d_in[3];
  const float* b_hh = (const float*)d_in[4];
  const float* fc_w = (const float*)d_in[5];
  const float* fc_b = (const float*)d_in[6];

  _Float16* wp = (_Float16*)d_ws;  // 192*128 f16 = 48 KiB

  pack_w<<<96, 256, 0, stream>>>(w_ih, w_hh, wp);
  gru_main<<<256, 256, 0, stream>>>(x, b_ih, b_hh, fc_w, fc_b, wp, (float*)d_out);
}